// Round 2
// 329.570 us; speedup vs baseline: 1.2698x; 1.2698x over previous
//
#include <hip/hip_runtime.h>

// Batched Viterbi decode: B=1024, S=512, T=64.
// R5 (resubmit; round-1 failure was container-infra, not kernel): value-only
// forward DP (add + fmax tree, no per-candidate argmax tracking) storing the
// pre-feat max vector vv_s[64] per step to a global workspace; backtrace
// recovers each needed backpointer EXACTLY via equality search:
//   bptr_s[n*] = first p with (vv_{s-1}[p]+feat[s-1][p]) + T[n*,p] == vv_s[n*]
// All adds replay forward adds bitwise; fmax returns one of its operands, so
// the equality set == argmax set and ctz(ballot) = first-index tie (jnp exact).
// The reference's reverse scan never consumes bptrs_0, so the init-vector
// special case never arises. Forward: ~130 VALU/step (depth-6 fmax tree, high
// ILP) vs R4's ~260 with 16-deep serial cmp/cndmask chains. Backtrace: 1
// ballot does all 64 comparisons; vv/feat loads prefetched 8 steps ahead
// (n*-independent). Host falls back to verified R4 if ws_size < 128 MiB.

#define B_ 1024
#define S_ 512
#define T_ 64
#define NEGV -10000.0f

// ---------------- R5 fast path ----------------
__global__ __launch_bounds__(64, 1) void viterbi_fwd_bt(
    const float* __restrict__ feats,   // [B, S, T]
    const float* __restrict__ trans,   // [T, T]
    float* __restrict__ out,           // [B + B*S]
    float* __restrict__ vv)            // workspace [B, S, T]: pre-feat max per step
{
    __shared__ float T_lds[T_ * T_];              // 16 KB transitions copy (row-major)
    __shared__ __align__(16) float fvbuf[2][T_];  // parity-double-buffered fv

    const int b = blockIdx.x;
    const int lane = threadIdx.x;      // forward: lane = next tag; backtrace: lane = prev tag

    // stage transitions into LDS for backtrace row reads (coalesced float4)
    {
        const float4* src = reinterpret_cast<const float4*>(trans);
        float4* dst = reinterpret_cast<float4*>(T_lds);
#pragma unroll
        for (int i = 0; i < 16; ++i) dst[i * 64 + lane] = src[i * 64 + lane];
    }

    // transitions row for next = lane (64 VGPRs)
    float t[T_];
#pragma unroll
    for (int p = 0; p < T_; p += 4) {
        const float4 v = *reinterpret_cast<const float4*>(trans + lane * T_ + p);
        t[p] = v.x; t[p + 1] = v.y; t[p + 2] = v.z; t[p + 3] = v.w;
    }
    const float tend = trans[(T_ - 1) * T_ + lane];   // transitions[END][lane]

    float fv = (lane == T_ - 2) ? 0.0f : NEGV;        // START = T-2
    fvbuf[0][lane] = fv;

    const float* fb = feats + (size_t)b * S_ * T_ + lane;
    float* vw = vv + (size_t)b * S_ * T_ + lane;

    // feat prefetch ring: 4 steps ahead
    float fc[4], fn[4];
#pragma unroll
    for (int k = 0; k < 4; ++k) fc[k] = fb[(size_t)k * T_];

#pragma unroll 1
    for (int s4 = 0; s4 < S_ / 4; ++s4) {
#pragma unroll
        for (int k = 0; k < 4; ++k) {
            int sp = 4 * s4 + 4 + k;
            sp = (sp < S_) ? sp : (S_ - 1);
            fn[k] = fb[(size_t)sp * T_];
        }
#pragma unroll
        for (int u = 0; u < 4; ++u) {
            const int s = 4 * s4 + u;
            const int rs = s & 1;
            // 64 candidates: add + fmax tree (no argmax tracking)
            float gm[16];
#pragma unroll
            for (int j = 0; j < 16; ++j) {
                const float4 v = *reinterpret_cast<const float4*>(&fvbuf[rs][4 * j]);
                const float c0 = v.x + t[4 * j + 0];
                const float c1 = v.y + t[4 * j + 1];
                const float c2 = v.z + t[4 * j + 2];
                const float c3 = v.w + t[4 * j + 3];
                gm[j] = fmaxf(fmaxf(c0, c1), fmaxf(c2, c3));
            }
#pragma unroll
            for (int off = 8; off >= 1; off >>= 1)
#pragma unroll
                for (int j = 0; j < off; ++j) gm[j] = fmaxf(gm[j], gm[j + off]);
            const float maxv = gm[0];

            vw[(size_t)s * T_] = maxv;        // store pre-feat viterbivars (exact)
            fv = maxv + fc[u];
            fvbuf[rs ^ 1][lane] = fv;
        }
#pragma unroll
        for (int k = 0; k < 4; ++k) fc[k] = fn[k];
    }

    // terminal: max/argmax over tags (butterfly, first-index ties)
    float v = fv + tend;
    int i = lane;
#pragma unroll
    for (int off = 1; off < 64; off <<= 1) {
        const float vo = __shfl_xor(v, off);
        const int io = __shfl_xor(i, off);
        const bool take = (vo > v) || ((vo == v) && (io < i));
        v = take ? vo : v;
        i = take ? io : i;
    }
    int ncur = __builtin_amdgcn_readfirstlane(i);
    if (lane == 0) out[b] = v;

    // ---- backtrace: equality search, 1 ballot per step ----
    asm volatile("s_waitcnt vmcnt(0)" ::: "memory");  // vv stores visible to our loads

    float A = vw[(size_t)(S_ - 1) * T_];              // vv_511 vector (lane p holds [p])
    // ring: slot k holds (vv_{s-1}, feat_{s-1}) for step s = 511-k
    float vvR[8], ffR[8];
#pragma unroll
    for (int k = 0; k < 8; ++k) {
        const int s = (S_ - 1) - k;
        vvR[k] = vw[(size_t)(s - 1) * T_];
        ffR[k] = fb[(size_t)(s - 1) * T_];
    }

    float emitv = 0.0f;
    float* outp = out + B_ + (size_t)b * S_;

#pragma unroll 1
    for (int c = 7; c >= 0; --c) {
#pragma unroll 1
        for (int g = 7; g >= 0; --g) {
            const int base = 64 * c + 8 * g;
#pragma unroll
            for (int kk = 0; kk < 8; ++kk) {
                const int s = base + 7 - kk;
                // emit tag at position s (carry BEFORE following backpointer)
                emitv = (lane == (s & 63)) ? (float)ncur : emitv;
                if (s > 0) {
                    // target = vv_s[n*] (exact stored max)
                    const float target = __int_as_float(
                        __builtin_amdgcn_readlane(__float_as_int(A), ncur));
                    // candidate for prev = lane: bitwise replay of forward adds
                    const float trow = T_lds[(ncur << 6) + lane];
                    const float cand = (vvR[kk] + ffR[kk]) + trow;
                    const unsigned long long m = __ballot(cand == target);
                    ncur = ((int)__builtin_ctzll(m)) & 63;   // first p == first-index argmax
                    A = vvR[kk];                             // becomes vv_{s-1} for next step
                    // refill slot kk for step s-8 (needs vv_{s-9}, feat_{s-9})
                    const int sp = (s >= 9) ? (s - 9) : 0;
                    vvR[kk] = vw[(size_t)sp * T_];
                    ffR[kk] = fb[(size_t)sp * T_];
                }
            }
        }
        outp[64 * c + lane] = emitv;   // coalesced 256B store per 64-step chunk
    }
}

// ---------------- R4 fallback (verified; used when workspace too small) ----------------
__global__ __launch_bounds__(64, 1) void viterbi_kernel(
    const float* __restrict__ feats,   // [B, S, T]
    const float* __restrict__ trans,   // [T, T]
    float* __restrict__ out)           // [B + B*S]
{
    __shared__ unsigned int bp[S_ / 4][T_];        // packed backpointers, 32 KB
    __shared__ __align__(16) float fvbuf[2][T_];   // parity-double-buffered fv

    const int b = blockIdx.x;
    const int lane = threadIdx.x;      // = next tag

    float t[T_];
#pragma unroll
    for (int p = 0; p < T_; p += 4) {
        const float4 v = *reinterpret_cast<const float4*>(trans + lane * T_ + p);
        t[p] = v.x; t[p + 1] = v.y; t[p + 2] = v.z; t[p + 3] = v.w;
    }
    const float tend = trans[(T_ - 1) * T_ + lane];

    float fv = (lane == T_ - 2) ? 0.0f : NEGV;
    fvbuf[0][lane] = fv;

    const float* fb = feats + (size_t)b * S_ * T_ + lane;

    float fc[4], fn[4];
#pragma unroll
    for (int k = 0; k < 4; ++k) fc[k] = fb[(size_t)k * T_];

#pragma unroll 1
    for (int s4 = 0; s4 < S_ / 4; ++s4) {
#pragma unroll
        for (int k = 0; k < 4; ++k) {
            int sp = 4 * s4 + 4 + k;
            sp = (sp < S_) ? sp : (S_ - 1);
            fn[k] = fb[(size_t)sp * T_];
        }

        unsigned int pack = 0;
#pragma unroll
        for (int u = 0; u < 4; ++u) {
            const int s = 4 * s4 + u;
            const int rs = s & 1;

            float fvl[T_];
#pragma unroll
            for (int j = 0; j < 16; ++j) {
                const float4 v = *reinterpret_cast<const float4*>(&fvbuf[rs][4 * j]);
                fvl[4 * j] = v.x; fvl[4 * j + 1] = v.y;
                fvl[4 * j + 2] = v.z; fvl[4 * j + 3] = v.w;
            }

            float bv[4]; int bi[4];
#pragma unroll
            for (int g = 0; g < 4; ++g) {
                float bestv = fvl[16 * g] + t[16 * g];
                int besti = 16 * g;
#pragma unroll
                for (int q = 1; q < 16; ++q) {
                    const int p = 16 * g + q;
                    const float c = fvl[p] + t[p];
                    const bool gt = c > bestv;
                    besti = gt ? p : besti;
                    bestv = gt ? c : bestv;
                }
                bv[g] = bestv; bi[g] = besti;
            }
            float BV = bv[0]; int BI = bi[0];
#pragma unroll
            for (int g = 1; g < 4; ++g) {
                const bool gt = bv[g] > BV;
                BI = gt ? bi[g] : BI;
                BV = gt ? bv[g] : BV;
            }

            fv = BV + fc[u];
            fvbuf[rs ^ 1][lane] = fv;
            pack |= ((unsigned int)BI) << (8 * u);
        }
        bp[s4][lane] = pack;

#pragma unroll
        for (int k = 0; k < 4; ++k) fc[k] = fn[k];
    }

    float v = fv + tend;
    int i = lane;
#pragma unroll
    for (int off = 1; off < 64; off <<= 1) {
        const float vo = __shfl_xor(v, off);
        const int io = __shfl_xor(i, off);
        const bool take = (vo > v) || ((vo == v) && (io < i));
        v = take ? vo : v;
        i = take ? io : i;
    }
    int tcur = __builtin_amdgcn_readfirstlane(i);
    if (lane == 0) out[b] = v;

    float* outp = out + B_ + (size_t)b * S_;
#pragma unroll 1
    for (int c = 7; c >= 0; --c) {
        unsigned int wd[16];
#pragma unroll
        for (int j = 0; j < 16; ++j)
            wd[j] = bp[16 * c + j][lane];

        int emit = 0;
#pragma unroll
        for (int k = 63; k >= 0; --k) {
            emit = (lane == k) ? tcur : emit;
            const int word = __builtin_amdgcn_readlane((int)wd[k >> 2], tcur);
            tcur = (word >> (8 * (k & 3))) & 0xff;
        }
        outp[64 * c + lane] = (float)emit;
    }
}

extern "C" void kernel_launch(void* const* d_in, const int* in_sizes, int n_in,
                              void* d_out, int out_size, void* d_ws, size_t ws_size,
                              hipStream_t stream) {
    const float* feats = (const float*)d_in[0];   // [B*S*T] f32
    const float* trans = (const float*)d_in[1];   // [T*T] f32
    float* out = (float*)d_out;                   // [B + B*S] f32

    const size_t need = (size_t)B_ * S_ * T_ * sizeof(float);  // 128 MiB
    if (d_ws != nullptr && ws_size >= need) {
        viterbi_fwd_bt<<<dim3(B_), dim3(T_), 0, stream>>>(feats, trans, out, (float*)d_ws);
    } else {
        viterbi_kernel<<<dim3(B_), dim3(T_), 0, stream>>>(feats, trans, out);
    }
}